// Round 1
// baseline (849.636 us; speedup 1.0000x reference)
//
#include <hip/hip_runtime.h>
#include <cstdint>

#define H 1024
#define W 2048
#define PS 16
#define ST 8
#define NHH ((H - PS) / ST + 1)   // 127
#define NWW ((W - PS) / ST + 1)   // 254
#define NPATCH (NHH * NWW)        // 32258
#define NN 256
#define MARGIN 1e-4f

// ws layout: [0..7] double sum, [8..11] uint n_used, [16..19] int byteflag
// byteflag: 0 => mask stored as int32, 1 => mask stored as 1-byte bools

__global__ void detect_mask_kernel(const unsigned int* __restrict__ mw,
                                   int* __restrict__ byteflag) {
    // Read first 1024 words (4 KB — safe under both interpretations, input is 2 MB+).
    // If mask were int32 0/1, every word is <= 1. If bytes, w.p. ~1 some word > 1.
    unsigned int w = mw[threadIdx.x];
    if (w > 1u) atomicOr(byteflag, 1);
}

__global__ __launch_bounds__(256) void patch_loss_kernel(
    const float* __restrict__ pred, const float* __restrict__ target,
    const void* __restrict__ mask, const float* __restrict__ noise,
    const int* __restrict__ byteflag,
    double* __restrict__ out_sum, unsigned int* __restrict__ out_n)
{
    __shared__ float sP[NN];
    __shared__ float sT[NN];
    __shared__ unsigned long long keyC[NN];
    __shared__ short sOrder[NN];
    __shared__ int wsum[4];
    __shared__ float wredA[4];
    __shared__ float wredC[4];

    const int p   = blockIdx.x;
    const int tid = threadIdx.x;
    const int ih = p / NWW;
    const int iw = p % NWW;
    const int row = ih * ST + (tid >> 4);
    const int col = iw * ST + (tid & 15);
    const int pix = row * W + col;

    const float pv = pred[pix];
    const float tv = target[pix];
    bool m;
    if (*byteflag) m = ((const unsigned char*)mask)[pix] != 0;
    else           m = ((const int*)mask)[pix] != 0;
    const float nz = noise[p * NN + tid];

    sP[tid] = pv;
    sT[tid] = tv;

    // ---- mask rank via ballot scan (matches cumsum(mask)-1) ----
    const unsigned long long bal = __ballot(m);
    const int lane = tid & 63;
    const int wid  = tid >> 6;
    const int incl = __popcll(bal & (~0ULL >> (63 - lane)));
    if (lane == 0) wsum[wid] = __popcll(bal);
    __syncthreads();
    int offset = 0;
    for (int wq = 0; wq < wid; ++wq) offset += wsum[wq];
    const int cnt = wsum[0] + wsum[1] + wsum[2] + wsum[3];
    const int rank = offset + incl - 1;  // valid only when m

    // ---- compact masked keys: (noise_bits << 8) | idx  (unique, stable) ----
    unsigned long long mykey = 0ULL;
    if (m) {
        mykey = ((unsigned long long)__float_as_uint(nz) << 8) | (unsigned)tid;
        keyC[rank] = mykey;
    }
    __syncthreads();

    // ---- counting rank among compacted keys (broadcast LDS reads) ----
    int pos = 0;
    int b = 0;
    for (; b + 4 <= cnt; b += 4) {
        const unsigned long long k0 = keyC[b + 0];
        const unsigned long long k1 = keyC[b + 1];
        const unsigned long long k2 = keyC[b + 2];
        const unsigned long long k3 = keyC[b + 3];
        pos += (int)(k0 < mykey) + (int)(k1 < mykey) +
               (int)(k2 < mykey) + (int)(k3 < mykey);
    }
    for (; b < cnt; ++b) pos += (int)(keyC[b] < mykey);
    if (m) sOrder[pos] = (short)tid;   // order[pos] = original index
    __syncthreads();

    // ---- partner lookup + hinge term ----
    float la = 0.0f;
    int   lc = 0;
    if (m) {
        const int partner = sOrder[rank];
        const float dt = tv - sT[partner];
        const float dp = pv - sP[partner] + MARGIN;
        const int sdt = (dt > 0.0f) - (dt < 0.0f);
        const int sdp = (dp > 0.0f) - (dp < 0.0f);
        if (sdt != sdp) { la = fabsf(dp); lc = 1; }
    }

    // ---- block reduction ----
    for (int off = 32; off > 0; off >>= 1) {
        la += __shfl_down(la, off);
        lc += __shfl_down(lc, off);
    }
    if (lane == 0) { wredA[wid] = la; wredC[wid] = (float)lc; }
    __syncthreads();
    if (tid == 0) {
        if (cnt > 0) {
            const float s = wredA[0] + wredA[1] + wredA[2] + wredA[3];
            const float c = wredC[0] + wredC[1] + wredC[2] + wredC[3];
            atomicAdd(out_sum, (double)(s / c));
            atomicAdd(out_n, 1u);
        }
    }
}

__global__ void finalize_kernel(const double* __restrict__ s,
                                const unsigned int* __restrict__ n,
                                float* __restrict__ out) {
    out[0] = (float)(s[0] / (double)n[0]);
}

extern "C" void kernel_launch(void* const* d_in, const int* in_sizes, int n_in,
                              void* d_out, int out_size, void* d_ws, size_t ws_size,
                              hipStream_t stream) {
    const float* pred   = (const float*)d_in[0];
    const float* target = (const float*)d_in[1];
    const void*  mask   = d_in[2];
    const float* noise  = (const float*)d_in[3];

    char* ws = (char*)d_ws;
    double*       sum  = (double*)(ws + 0);
    unsigned int* nptr = (unsigned int*)(ws + 8);
    int*          flag = (int*)(ws + 16);

    hipMemsetAsync(ws, 0, 32, stream);
    detect_mask_kernel<<<1, 1024, 0, stream>>>((const unsigned int*)mask, flag);
    patch_loss_kernel<<<NPATCH, 256, 0, stream>>>(pred, target, mask, noise,
                                                  flag, sum, nptr);
    finalize_kernel<<<1, 1, 0, stream>>>(sum, nptr, (float*)d_out);
}

// Round 2
// 185.640 us; speedup vs baseline: 4.5768x; 4.5768x over previous
//
#include <hip/hip_runtime.h>
#include <cstdint>

#define H 1024
#define W 2048
#define PS 16
#define ST 8
#define NHH ((H - PS) / ST + 1)   // 127
#define NWW ((W - PS) / ST + 1)   // 254
#define NPATCH (NHH * NWW)        // 32258
#define NN 256
#define MARGIN 1e-4f

// ws layout:
//   [0      .. 131071]  float loss[32768]   (per-patch loss, 0 if invalid)
//   [131072 .. 262143]  float valid[32768]  (1.0 / 0.0)
//   [262144 .. 262159]  float acc[2] (sum, count) + int byteflag + pad
#define WS_LOSS_OFF   0
#define WS_VALID_OFF  131072
#define WS_ACC_OFF    262144

__global__ void detect_mask_kernel(const unsigned int* __restrict__ mw,
                                   int* __restrict__ byteflag) {
    unsigned int w = mw[threadIdx.x];
    if (w > 1u) atomicOr(byteflag, 1);
}

__global__ __launch_bounds__(256) void patch_loss_kernel(
    const float* __restrict__ pred, const float* __restrict__ target,
    const void* __restrict__ mask, const float* __restrict__ noise,
    const int* __restrict__ byteflag,
    float* __restrict__ out_loss, float* __restrict__ out_valid)
{
    __shared__ float sP[NN];
    __shared__ float sT[NN];
    __shared__ unsigned long long keyC[NN];
    __shared__ short sOrder[NN];
    __shared__ int wsum[4];
    __shared__ float wredA[4];
    __shared__ float wredC[4];

    const int p   = blockIdx.x;
    const int tid = threadIdx.x;
    const int ih = p / NWW;
    const int iw = p % NWW;
    const int row = ih * ST + (tid >> 4);
    const int col = iw * ST + (tid & 15);
    const int pix = row * W + col;

    const float pv = pred[pix];
    const float tv = target[pix];
    bool m;
    if (*byteflag) m = ((const unsigned char*)mask)[pix] != 0;
    else           m = ((const int*)mask)[pix] != 0;
    const float nz = noise[p * NN + tid];

    sP[tid] = pv;
    sT[tid] = tv;

    // ---- mask rank via ballot scan (matches cumsum(mask)-1) ----
    const unsigned long long bal = __ballot(m);
    const int lane = tid & 63;
    const int wid  = tid >> 6;
    const int incl = __popcll(bal & (~0ULL >> (63 - lane)));
    if (lane == 0) wsum[wid] = __popcll(bal);
    __syncthreads();
    int offset = 0;
    for (int wq = 0; wq < wid; ++wq) offset += wsum[wq];
    const int cnt = wsum[0] + wsum[1] + wsum[2] + wsum[3];
    const int rank = offset + incl - 1;  // valid only when m

    // ---- compact masked keys: (noise_bits << 8) | idx  (unique, stable) ----
    unsigned long long mykey = 0ULL;
    if (m) {
        mykey = ((unsigned long long)__float_as_uint(nz) << 8) | (unsigned)tid;
        keyC[rank] = mykey;
    }
    __syncthreads();

    // ---- counting rank among compacted keys (broadcast LDS reads) ----
    int pos = 0;
    int b = 0;
    for (; b + 4 <= cnt; b += 4) {
        const unsigned long long k0 = keyC[b + 0];
        const unsigned long long k1 = keyC[b + 1];
        const unsigned long long k2 = keyC[b + 2];
        const unsigned long long k3 = keyC[b + 3];
        pos += (int)(k0 < mykey) + (int)(k1 < mykey) +
               (int)(k2 < mykey) + (int)(k3 < mykey);
    }
    for (; b < cnt; ++b) pos += (int)(keyC[b] < mykey);
    if (m) sOrder[pos] = (short)tid;   // order[pos] = original index
    __syncthreads();

    // ---- partner lookup + hinge term ----
    float la = 0.0f;
    int   lc = 0;
    if (m) {
        const int partner = sOrder[rank];
        const float dt = tv - sT[partner];
        const float dp = pv - sP[partner] + MARGIN;
        const int sdt = (dt > 0.0f) - (dt < 0.0f);
        const int sdp = (dp > 0.0f) - (dp < 0.0f);
        if (sdt != sdp) { la = fabsf(dp); lc = 1; }
    }

    // ---- block reduction ----
    for (int off = 32; off > 0; off >>= 1) {
        la += __shfl_down(la, off);
        lc += __shfl_down(lc, off);
    }
    if (lane == 0) { wredA[wid] = la; wredC[wid] = (float)lc; }
    __syncthreads();
    if (tid == 0) {
        float pl = 0.0f, hv = 0.0f;
        if (cnt > 0) {
            const float s = wredA[0] + wredA[1] + wredA[2] + wredA[3];
            const float c = wredC[0] + wredC[1] + wredC[2] + wredC[3];
            pl = s / c;
            hv = 1.0f;
        }
        out_loss[p]  = pl;
        out_valid[p] = hv;
    }
}

__global__ __launch_bounds__(256) void reduce_kernel(
    const float* __restrict__ loss, const float* __restrict__ valid,
    float* __restrict__ acc)
{
    __shared__ float sa[4], sb[4];
    float a = 0.0f, b = 0.0f;
    for (int i = blockIdx.x * blockDim.x + threadIdx.x; i < NPATCH;
         i += gridDim.x * blockDim.x) {
        a += loss[i];
        b += valid[i];
    }
    for (int off = 32; off > 0; off >>= 1) {
        a += __shfl_down(a, off);
        b += __shfl_down(b, off);
    }
    const int lane = threadIdx.x & 63, wid = threadIdx.x >> 6;
    if (lane == 0) { sa[wid] = a; sb[wid] = b; }
    __syncthreads();
    if (threadIdx.x == 0) {
        atomicAdd(&acc[0], sa[0] + sa[1] + sa[2] + sa[3]);
        atomicAdd(&acc[1], sb[0] + sb[1] + sb[2] + sb[3]);
    }
}

__global__ void finalize_kernel(const float* __restrict__ acc,
                                float* __restrict__ out) {
    out[0] = acc[0] / acc[1];
}

extern "C" void kernel_launch(void* const* d_in, const int* in_sizes, int n_in,
                              void* d_out, int out_size, void* d_ws, size_t ws_size,
                              hipStream_t stream) {
    const float* pred   = (const float*)d_in[0];
    const float* target = (const float*)d_in[1];
    const void*  mask   = d_in[2];
    const float* noise  = (const float*)d_in[3];

    char* ws = (char*)d_ws;
    float* ws_loss  = (float*)(ws + WS_LOSS_OFF);
    float* ws_valid = (float*)(ws + WS_VALID_OFF);
    float* acc      = (float*)(ws + WS_ACC_OFF);
    int*   flag     = (int*)(ws + WS_ACC_OFF + 8);

    hipMemsetAsync(ws + WS_ACC_OFF, 0, 16, stream);
    detect_mask_kernel<<<1, 1024, 0, stream>>>((const unsigned int*)mask, flag);
    patch_loss_kernel<<<NPATCH, 256, 0, stream>>>(pred, target, mask, noise,
                                                  flag, ws_loss, ws_valid);
    reduce_kernel<<<128, 256, 0, stream>>>(ws_loss, ws_valid, acc);
    finalize_kernel<<<1, 1, 0, stream>>>(acc, (float*)d_out);
}

// Round 3
// 173.630 us; speedup vs baseline: 4.8934x; 1.0692x over previous
//
#include <hip/hip_runtime.h>
#include <cstdint>

#define H 1024
#define W 2048
#define PS 16
#define ST 8
#define NHH ((H - PS) / ST + 1)   // 127
#define NWW ((W - PS) / ST + 1)   // 254
#define NPATCH (NHH * NWW)        // 32258
#define NN 256
#define MARGIN 1e-4f
#define RED_BLOCKS 128

// ws layout:
//   [0      .. 131071]  float loss[32768]   (per-patch loss, 0 if invalid)
//   [131072 .. 262143]  float valid[32768]  (1.0 / 0.0)
//   [262144 .. ]        float acc[2], uint ticket, int byteflag
#define WS_LOSS_OFF   0
#define WS_VALID_OFF  131072
#define WS_ACC_OFF    262144

__global__ void detect_mask_kernel(const unsigned int* __restrict__ mw,
                                   int* __restrict__ byteflag) {
    unsigned int w = mw[threadIdx.x];
    if (w > 1u) atomicOr(byteflag, 1);
}

__global__ __launch_bounds__(256) void patch_loss_kernel(
    const float* __restrict__ pred, const float* __restrict__ target,
    const void* __restrict__ mask, const float* __restrict__ noise,
    const int* __restrict__ byteflag,
    float* __restrict__ out_loss, float* __restrict__ out_valid)
{
    __shared__ float sP[NN];
    __shared__ float sT[NN];
    __shared__ unsigned long long keyC[NN];
    __shared__ short sOrder[NN];
    __shared__ int wsum[4];
    __shared__ float wredA[4];
    __shared__ float wredC[4];

    const int p   = blockIdx.x;
    const int tid = threadIdx.x;
    const int ih = p / NWW;
    const int iw = p % NWW;
    const int row = ih * ST + (tid >> 4);
    const int col = iw * ST + (tid & 15);
    const int pix = row * W + col;

    const float pv = pred[pix];
    const float tv = target[pix];
    bool m;
    if (*byteflag) m = ((const unsigned char*)mask)[pix] != 0;
    else           m = ((const int*)mask)[pix] != 0;
    const float nz = noise[p * NN + tid];

    sP[tid] = pv;
    sT[tid] = tv;

    // ---- mask rank via ballot scan (matches cumsum(mask)-1) ----
    const unsigned long long bal = __ballot(m);
    const int lane = tid & 63;
    const int wid  = tid >> 6;
    const int incl = __popcll(bal & (~0ULL >> (63 - lane)));
    if (lane == 0) wsum[wid] = __popcll(bal);
    __syncthreads();
    int offset = 0;
    for (int wq = 0; wq < wid; ++wq) offset += wsum[wq];
    const int cnt = wsum[0] + wsum[1] + wsum[2] + wsum[3];
    const int rank = offset + incl - 1;  // valid only when m

    // ---- compact masked keys: (noise_bits << 8) | idx  (unique, stable) ----
    if (m) {
        keyC[rank] = ((unsigned long long)__float_as_uint(nz) << 8) | (unsigned)tid;
    }
    __syncthreads();

    // ---- counting rank: thread r ranks compacted key r (waves beyond cnt skip) ----
    if (tid < cnt) {
        const unsigned long long mykey = keyC[tid];
        int pos = 0;
        int b = 0;
        for (; b + 4 <= cnt; b += 4) {
            const unsigned long long k0 = keyC[b + 0];
            const unsigned long long k1 = keyC[b + 1];
            const unsigned long long k2 = keyC[b + 2];
            const unsigned long long k3 = keyC[b + 3];
            pos += (int)(k0 < mykey) + (int)(k1 < mykey) +
                   (int)(k2 < mykey) + (int)(k3 < mykey);
        }
        for (; b < cnt; ++b) pos += (int)(keyC[b] < mykey);
        sOrder[pos] = (short)(mykey & 0xFF);   // order[pos] = original index
    }
    __syncthreads();

    // ---- partner lookup + hinge term ----
    float la = 0.0f;
    int   lc = 0;
    if (m) {
        const int partner = sOrder[rank];
        const float dt = tv - sT[partner];
        const float dp = pv - sP[partner] + MARGIN;
        const int sdt = (dt > 0.0f) - (dt < 0.0f);
        const int sdp = (dp > 0.0f) - (dp < 0.0f);
        if (sdt != sdp) { la = fabsf(dp); lc = 1; }
    }

    // ---- block reduction ----
    for (int off = 32; off > 0; off >>= 1) {
        la += __shfl_down(la, off);
        lc += __shfl_down(lc, off);
    }
    if (lane == 0) { wredA[wid] = la; wredC[wid] = (float)lc; }
    __syncthreads();
    if (tid == 0) {
        float pl = 0.0f, hv = 0.0f;
        if (cnt > 0) {
            const float s = wredA[0] + wredA[1] + wredA[2] + wredA[3];
            const float c = wredC[0] + wredC[1] + wredC[2] + wredC[3];
            pl = s / c;
            hv = 1.0f;
        }
        out_loss[p]  = pl;
        out_valid[p] = hv;
    }
}

__global__ __launch_bounds__(256) void reduce_finalize_kernel(
    const float* __restrict__ loss, const float* __restrict__ valid,
    float* __restrict__ acc, unsigned int* __restrict__ ticket,
    float* __restrict__ out)
{
    __shared__ float sa[4], sb[4];
    float a = 0.0f, b = 0.0f;
    for (int i = blockIdx.x * blockDim.x + threadIdx.x; i < NPATCH;
         i += gridDim.x * blockDim.x) {
        a += loss[i];
        b += valid[i];
    }
    for (int off = 32; off > 0; off >>= 1) {
        a += __shfl_down(a, off);
        b += __shfl_down(b, off);
    }
    const int lane = threadIdx.x & 63, wid = threadIdx.x >> 6;
    if (lane == 0) { sa[wid] = a; sb[wid] = b; }
    __syncthreads();
    if (threadIdx.x == 0) {
        atomicAdd(&acc[0], sa[0] + sa[1] + sa[2] + sa[3]);
        atomicAdd(&acc[1], sb[0] + sb[1] + sb[2] + sb[3]);
        __threadfence();
        const unsigned int old = atomicAdd(ticket, 1u);
        if (old == (unsigned int)(gridDim.x - 1)) {
            // atomic reads: coherent at device scope across XCDs
            const float s = atomicAdd(&acc[0], 0.0f);
            const float c = atomicAdd(&acc[1], 0.0f);
            out[0] = s / c;
        }
    }
}

extern "C" void kernel_launch(void* const* d_in, const int* in_sizes, int n_in,
                              void* d_out, int out_size, void* d_ws, size_t ws_size,
                              hipStream_t stream) {
    const float* pred   = (const float*)d_in[0];
    const float* target = (const float*)d_in[1];
    const void*  mask   = d_in[2];
    const float* noise  = (const float*)d_in[3];

    char* ws = (char*)d_ws;
    float*        ws_loss  = (float*)(ws + WS_LOSS_OFF);
    float*        ws_valid = (float*)(ws + WS_VALID_OFF);
    float*        acc      = (float*)(ws + WS_ACC_OFF);
    unsigned int* ticket   = (unsigned int*)(ws + WS_ACC_OFF + 8);
    int*          flag     = (int*)(ws + WS_ACC_OFF + 12);

    hipMemsetAsync(ws + WS_ACC_OFF, 0, 16, stream);
    detect_mask_kernel<<<1, 1024, 0, stream>>>((const unsigned int*)mask, flag);
    patch_loss_kernel<<<NPATCH, 256, 0, stream>>>(pred, target, mask, noise,
                                                  flag, ws_loss, ws_valid);
    reduce_finalize_kernel<<<RED_BLOCKS, 256, 0, stream>>>(ws_loss, ws_valid,
                                                           acc, ticket,
                                                           (float*)d_out);
}